// Round 7
// baseline (1807.093 us; speedup 1.0000x reference)
//
#include <hip/hip_runtime.h>
#include <math.h>

#define NVIEW 720
#define NDCT  1024
#define NZ    32
#define NX    512
#define NY    512

#define TS   32      // pixel tile 32x32
#define ZG   16      // z per block; 2 z-groups, packed layout split by group
#define NR   48      // staged rows: 31*(|c|+|s|)+1 <= 44.9, +1 for i+1, +pad -> 48
#define RS   20      // dwords per staged row (16 data + 4 pad; 80 B). b128 start of
                     // row r = 20r mod 32: injective mod 8 -> alias only dr in
                     // {8,16,24}. Wave i0-spread kept <= 21 (8x8 lane footprint)
                     // so alias pairs are rare: R1-measured-free class.
#define GSTRIDE ((size_t)NVIEW * NDCT * 16)   // dw per z-group region (47.2 MB)

typedef unsigned int uint;

#if __has_builtin(__builtin_amdgcn_fdot2)
#define USE_FDOT2 1
typedef _Float16 half2v __attribute__((ext_vector_type(2)));
#else
#define USE_FDOT2 0
#endif

// Round fp32 -> bf16 bits (RNE).
__device__ __forceinline__ uint f2bf_rne(float f) {
    uint u = __float_as_uint(f);
    return (u + 0x7fffu + ((u >> 16) & 1u)) >> 16;
}

// Packed word for (v, i, z):
//  fdot2 path:  lo16 = f16(g0 = p[i]), hi16 = f16(d = p[i+1]-p[i])
//               consumer: acc = v_dot2_f32_f16(word, {1.0, w}, acc)
//  fallback:    hi16 = dithered bf16(g0), lo16 = bf16(d)
__device__ __forceinline__ uint pack_word(float a, float b) {
#if USE_FDOT2
    union { _Float16 h[2]; uint u; } r;
    r.h[0] = (_Float16)a;         // g0 in low half
    r.h[1] = (_Float16)(b - a);   // d  in high half
    return r.u;
#else
    uint lo = f2bf_rne(b - a);
    uint u  = (f2bf_rne(a) << 16) | lo;
    uint up = u + 0x10000u, um = u - 0x10000u;
    float e0 = fabsf(__uint_as_float(u)  - a);
    float e1 = fabsf(__uint_as_float(up) - a);
    float e2 = fabsf(__uint_as_float(um) - a);
    if (e1 < e0) { u = up; e0 = e1; }
    if (e2 < e0) { u = um; }
    return u;
#endif
}

// packed[g][v][i][z16], g = z>>4: z-group-split so each bp block reads only
// full 128B lines (2 rows/line) from its own region.  (R6-proven, unchanged.)
__global__ __launch_bounds__(64) void pack_kernel(const float* __restrict__ x,
                                                  uint* __restrict__ packed) {
    __shared__ uint tr[64 * 33];             // [i_local][z], stride 33 -> conflict-free
    const int l  = threadIdx.x;              // 0..63
    const int v  = blockIdx.x;               // 0..719
    const int ib = blockIdx.y * 64;          // i block base
    const bool last = (ib + 64 >= NDCT);
    const float* rowbase = x + (size_t)v * NDCT + ib;

    float pre = 0.0f;
    if (l < NZ && !last) pre = rowbase[(size_t)l * (NVIEW * NDCT) + 64];

    for (int z = 0; z < NZ; ++z) {
        const float* r = rowbase + (size_t)z * (NVIEW * NDCT);
        float a   = r[l];                    // coalesced 256B
        float a64 = __shfl(pre, z);
        float b   = __shfl(a, l + 1);
        if (l == 63) b = a64;                // neighbor across wave boundary
        tr[l * 33 + z] = pack_word(a, b);
    }
    __syncthreads();

    #pragma unroll
    for (int it = 0; it < 8; ++it) {
        int c  = it * 64 + l;                // chunk 0..511
        int il = c >> 3;
        int zc = (c & 7) * 4;
        int gg = zc >> 4;                    // z-group region
        int zl = zc & 15;
        uint4 w4;
        w4.x = tr[il * 33 + zc + 0];
        w4.y = tr[il * 33 + zc + 1];
        w4.z = tr[il * 33 + zc + 2];
        w4.w = tr[il * 33 + zc + 3];
        uint* dst = packed + (size_t)gg * GSTRIDE
                  + ((size_t)(v * NDCT + ib + il) << 4) + zl;
        *(uint4*)dst = w4;                   // 16B chunks, region-contiguous
    }
}

#if USE_FDOT2
#define SAMP(A, zz, uu, WP, WF) do { \
    union { uint q; half2v h; } _c; _c.q = (uu); \
    A[zz] = __builtin_amdgcn_fdot2(_c.h, (WP), A[zz], false); \
} while (0)
#else
#define SAMP(A, zz, uu, WP, WF) do { \
    A[zz] += __uint_as_float(uu); \
    A[zz]  = fmaf((WF), __uint_as_float((uu) << 16), A[zz]); \
} while (0)
#endif

#define SAMPLE16(A, WP, WF) do { \
    SAMP(A, 0, q0.x, WP, WF); SAMP(A, 1, q0.y, WP, WF); \
    SAMP(A, 2, q0.z, WP, WF); SAMP(A, 3, q0.w, WP, WF); \
    SAMP(A, 4, q1.x, WP, WF); SAMP(A, 5, q1.y, WP, WF); \
    SAMP(A, 6, q1.z, WP, WF); SAMP(A, 7, q1.w, WP, WF); \
    SAMP(A, 8, q2.x, WP, WF); SAMP(A, 9, q2.y, WP, WF); \
    SAMP(A,10, q2.z, WP, WF); SAMP(A,11, q2.w, WP, WF); \
    SAMP(A,12, q3.x, WP, WF); SAMP(A,13, q3.y, WP, WF); \
    SAMP(A,14, q3.z, WP, WF); SAMP(A,15, q3.w, WP, WF); \
} while (0)

// 32x32 pixel tile, 512 threads, 2 adjacent x-pixels + 16 z per thread.
// vs R6, two changes:
//  (1) lane remap: wave = 8 x-pairs x 8 y (quadrant per wave) -> wave i0-spread
//      back to <= 21 (R1's measured-low-conflict footprint; R6's 16x4 wave
//      quadrupled SQ_LDS_BANK_CONFLICT and cost +85us).
//  (2) px1 gather moved LDS -> GLOBAL (L1-resident 3KB/view window), masked by
//      i1 != i0, into registers defined and consumed WITHIN one iteration (the
//      cross-barrier conditional carry was R2's scratch-demotion bug; tripwire:
//      WRITE_SIZE must stay 32768 KB). LDS keeps px0 only: the two gather
//      streams now run on different pipes in parallel.
__global__ __launch_bounds__(512, 4) void bp_lds(const uint* __restrict__ packed,
                                                 float* __restrict__ out) {
    __shared__ float4 tab[NVIEW];                        // 11520 B
    __shared__ __align__(16) uint stage[2][NR * RS];     // 2 x 3840 B

    const int tid = threadIdx.x;                         // 0..511
    const int g   = blockIdx.z;                          // z-group 0..1
    const float xf0 = (float)(int)(blockIdx.x * TS) - 255.5f;
    const float yf0 = (float)(int)(blockIdx.y * TS) - 255.5f;

    // Per-view cos/sin + block-uniform floor(t_min) folded as bval = 511.5 - imin.
    // bval fold perturbs t by <= 1 ULP(512); trunc at 0 and NR slack absorb it.
    for (int v = tid; v < NVIEW; v += 512) {
        float th = (float)v * (float)(M_PI / NVIEW);
        float s, c;
        sincosf(th, &s, &c);
        float b0 = fmaf(yf0, s, 511.5f);
        float b1 = fmaf(yf0 + (float)(TS - 1), s, 511.5f);
        float t00 = fmaf(xf0, c, b0);
        float t10 = fmaf(xf0 + (float)(TS - 1), c, b0);
        float t01 = fmaf(xf0, c, b1);
        float t11 = fmaf(xf0 + (float)(TS - 1), c, b1);
        int imin = (int)fminf(fminf(t00, t10), fminf(t01, t11));
        tab[v] = make_float4(c, s, 511.5f - (float)imin, __int_as_float(imin));
    }
    __syncthreads();

    // 8x8 lane footprint; wave = quadrant (xh: 16-px half, yq: 8-row band)
    const int lane = tid & 63;
    const int wv   = tid >> 6;
    const int lx   = lane & 7, ly = lane >> 3;
    const int xh   = wv & 1,   yq = wv >> 1;
    const int x0   = blockIdx.x * TS + xh * 16 + lx * 2;   // even
    const int y    = blockIdx.y * TS + yq * 8 + ly;
    const float xf = (float)x0 - 255.5f;
    const float yf = (float)y  - 255.5f;

    float acc0[ZG], acc1[ZG];
    #pragma unroll
    for (int z = 0; z < ZG; ++z) { acc0[z] = 0.0f; acc1[z] = 0.0f; }

    // Staging: NR rows x 16 dw = 192 x4-chunks over 8 waves (24 lanes each).
    // Global span is CONTIGUOUS 3072 B (region layout): 24 full 128B lines.
    const bool sact = (lane < 24);
    const int  slot = wv * 24 + lane;        // 0..191
    const int  sr   = slot >> 2;             // staged row 0..47
    const int  sch  = slot & 3;              // 16B chunk 0..3
    const size_t sg_off = ((size_t)sr << 4) + (sch << 2);   // dw off within window
    const int  swr  = sr * RS + (sch << 2);                 // LDS dw off
    const uint* greg = packed + (size_t)g * GSTRIDE;        // this block's region

    // ---- prologue: stage view 0 into buffer 0 ----
    float4 t4 = tab[0];
    uint4 st;
    if (sact) {
        st = *(const uint4*)(greg + ((size_t)__float_as_int(t4.w) << 4) + sg_off);
        *(uint4*)&stage[0][swr] = st;
    }
    __syncthreads();

    #pragma unroll 2
    for (int v = 0; v < NVIEW; ++v) {
        // [A] next-view tab read + staging load (published at [F]; ~full view flight)
        float4 t4n = t4;
        if (v + 1 < NVIEW) t4n = tab[v + 1];
        if (sact && v + 1 < NVIEW) {
            st = *(const uint4*)(greg + ((size_t)(v + 1) << 14)
                                 + ((size_t)__float_as_int(t4n.w) << 4) + sg_off);
        }

        const float c = t4.x;
        const int  imin_i = __float_as_int(t4.w);
        float t0 = fmaf(xf, c, fmaf(yf, t4.y, t4.z));   // t - imin, >= -1ulp
        float t1 = t0 + c;
        int   i0 = (int)t0;                              // trunc(-eps) = 0: safe
        int   i1 = (int)t1;                              // in [0, 46] (corner bound)
        float w0 = t0 - (float)i0;
        float w1 = t1 - (float)i1;

#if USE_FDOT2
        half2v wp0; wp0[0] = (_Float16)1.0f; wp0[1] = (_Float16)w0;
        half2v wp1; wp1[0] = (_Float16)1.0f; wp1[1] = (_Float16)w1;
#else
        const int wp0 = 0, wp1 = 0;  // unused tokens in fallback
#endif

        // [B] px1 row from GLOBAL (L1-hit: same 3KB window all waves read),
        // masked; regs r0..r3 are fresh this iteration (no cross-iter carry).
        const bool m = (i1 != i0);
        uint4 r0, r1, r2, r3;
        if (m) {
            const uint* gp = greg + ((size_t)v << 14)
                           + ((size_t)(imin_i + i1) << 4);
            r0 = *(const uint4*)(gp);
            r1 = *(const uint4*)(gp + 4);
            r2 = *(const uint4*)(gp + 8);
            r3 = *(const uint4*)(gp + 12);
        }

        // [C] px0 gather from LDS: 4x b128 off one base (imm offsets 0/16/32/48 B)
        const uint* sp = stage[v & 1] + i0 * RS;
        uint4 q0 = *(const uint4*)(sp);
        uint4 q1 = *(const uint4*)(sp + 4);
        uint4 q2 = *(const uint4*)(sp + 8);
        uint4 q3 = *(const uint4*)(sp + 12);

        SAMPLE16(acc0, wp0, w0);

        // [D] merge px1 row where it differs; lanes with i1==i0 keep q (correct).
        q0.x = m ? r0.x : q0.x; q0.y = m ? r0.y : q0.y;
        q0.z = m ? r0.z : q0.z; q0.w = m ? r0.w : q0.w;
        q1.x = m ? r1.x : q1.x; q1.y = m ? r1.y : q1.y;
        q1.z = m ? r1.z : q1.z; q1.w = m ? r1.w : q1.w;
        q2.x = m ? r2.x : q2.x; q2.y = m ? r2.y : q2.y;
        q2.z = m ? r2.z : q2.z; q2.w = m ? r2.w : q2.w;
        q3.x = m ? r3.x : q3.x; q3.y = m ? r3.y : q3.y;
        q3.z = m ? r3.z : q3.z; q3.w = m ? r3.w : q3.w;

        SAMPLE16(acc1, wp1, w1);

        // [F] publish view v+1 stage (vmcnt waits only on st, issued at [A])
        if (sact && v + 1 < NVIEW) *(uint4*)&stage[(v + 1) & 1][swr] = st;
        // [G] one barrier per view: orders iter-(v+1) writes of a buffer after
        // all iter-v reads of it -> race-free double buffer
        __syncthreads();
        t4 = t4n;
    }

    const float scale = 0.0043633231299858236f;  // pi / 720
    #pragma unroll
    for (int lz = 0; lz < ZG; ++lz) {
        float2 o = make_float2(acc0[lz] * scale, acc1[lz] * scale);
        *(float2*)(out + (((size_t)(g * ZG + lz)) * NY + y) * NX + x0) = o;
    }
}

// Fallback (ws too small for packed array): direct fp32, two loads per sample.
__global__ __launch_bounds__(256) void bp_direct(const float* __restrict__ xin,
                                                 float* __restrict__ out) {
    __shared__ float2 cs[NVIEW];
    int lt = threadIdx.y * 64 + threadIdx.x;
    for (int v = lt; v < NVIEW; v += 256) {
        float th = (float)v * (float)(M_PI / NVIEW);
        float s, c;
        sincosf(th, &s, &c);
        cs[v] = make_float2(c, s);
    }
    __syncthreads();

    int x = blockIdx.x * 64 + threadIdx.x;
    int y = blockIdx.y * 4 + threadIdx.y;
    float xf = (float)x - 255.5f;
    float yf = (float)y - 255.5f;

    float acc[NZ];
    #pragma unroll
    for (int z = 0; z < NZ; ++z) acc[z] = 0.0f;

    for (int v = 0; v < NVIEW; ++v) {
        float2 a = cs[v];
        float t  = fmaf(xf, a.x, fmaf(yf, a.y, 511.5f));
        int   i0 = (int)t;
        float w  = t - (float)i0;
        const float* p = xin + (size_t)v * NDCT + i0;
        #pragma unroll
        for (int z = 0; z < NZ; ++z) {
            float g0 = p[(size_t)z * NVIEW * NDCT];
            float g1 = p[(size_t)z * NVIEW * NDCT + 1];
            acc[z] += fmaf(w, g1 - g0, g0);
        }
    }

    const float scale = 0.0043633231299858236f;
    #pragma unroll
    for (int z = 0; z < NZ; ++z) {
        out[((size_t)z * NY + y) * NX + x] = acc[z] * scale;
    }
}

extern "C" void kernel_launch(void* const* d_in, const int* in_sizes, int n_in,
                              void* d_out, int out_size, void* d_ws, size_t ws_size,
                              hipStream_t stream) {
    const float* x = (const float*)d_in[0];
    float* out = (float*)d_out;

    const size_t packed_bytes = 2 * GSTRIDE * sizeof(uint);   // 94.4 MB

    if (ws_size >= packed_bytes) {
        uint* packed = (uint*)d_ws;
        pack_kernel<<<dim3(NVIEW, NDCT / 64), 64, 0, stream>>>(x, packed);
        bp_lds<<<dim3(NX / TS, NY / TS, 2), dim3(512), 0, stream>>>(packed, out);
    } else {
        bp_direct<<<dim3(NX / 64, NY / 4), dim3(64, 4), 0, stream>>>(x, out);
    }
}